// Round 1
// baseline (194.898 us; speedup 1.0000x reference)
//
#include <hip/hip_runtime.h>
#include <math.h>

#define Cc 96
#define Hh 128
#define Ww 128
#define HWsz (Hh*Ww)
#define TW 16
#define TH 8
#define LROW 18
#define LPLANE 180   // 10 rows * 18 cols

__global__ __launch_bounds__(128)
void alpf_fused(const float* __restrict__ x,
                const float* __restrict__ dw_w,
                const float* __restrict__ dw_b,
                const float* __restrict__ pw1_w,
                const float* __restrict__ pw1_b,
                const float* __restrict__ pw2_w,
                const float* __restrict__ pw2_b,
                float* __restrict__ out)
{
    __shared__ float lx[Cc * LPLANE];   // 69120 B

    const int tid = threadIdx.x;
    const int x0 = blockIdx.x * TW;
    const int y0 = blockIdx.y * TH;
    const int b  = blockIdx.z;
    const float* __restrict__ xb = x + (size_t)b * Cc * HWsz;

    // ---------- halo load: rows [y0-1, y0+8], cols [x0-1, x0+16] ----------
    {
        const int e1 = tid;              // 0..127
        const int e2 = tid + 128;        // 128..255, valid if < 180
        const int r1 = e1 / LROW, q1 = e1 % LROW;
        const int r2 = e2 / LROW, q2 = e2 % LROW;
        const int gy1 = y0 - 1 + r1, gx1 = x0 - 1 + q1;
        const int gy2 = y0 - 1 + r2, gx2 = x0 - 1 + q2;
        const bool ok1 = (gy1 >= 0) && (gy1 < Hh) && (gx1 >= 0) && (gx1 < Ww);
        const bool v2  = (e2 < LPLANE);
        const bool ok2 = v2 && (gy2 >= 0) && (gy2 < Hh) && (gx2 >= 0) && (gx2 < Ww);
        const int g1 = gy1 * Ww + gx1;
        const int g2 = gy2 * Ww + gx2;
        for (int c = 0; c < Cc; ++c) {
            const float* xc = xb + c * HWsz;
            float a = ok1 ? xc[g1] : 0.f;
            lx[c * LPLANE + e1] = a;
            if (v2) {
                float bv = ok2 ? xc[g2] : 0.f;
                lx[c * LPLANE + e2] = bv;
            }
        }
    }
    __syncthreads();

    // ---------- per-pixel compute; lane -> pixel ----------
    const int lane = tid & 63;
    const int wv = tid >> 6;                  // 0..1
    const int sx = lane & 15;                 // 0..15
    const int sy = (lane >> 4) + (wv << 2);   // 0..7
    const int pbase = sy * LROW + sx;         // top-left of 3x3 patch in a plane

    // pw1 accumulators (48 independent chains in VGPRs)
    float t[48];
    #pragma unroll
    for (int o = 0; o < 48; ++o) t[o] = pw1_b[o];

    for (int c = 0; c < Cc; ++c) {
        const float* lp = lx + c * LPLANE + pbase;
        const float p0 = lp[0],        p1 = lp[1],        p2 = lp[2];
        const float p3 = lp[LROW],     p4 = lp[LROW+1],   p5 = lp[LROW+2];
        const float p6 = lp[2*LROW],   p7 = lp[2*LROW+1], p8 = lp[2*LROW+2];
        const float* wc = dw_w + c * 9;
        float a0 = fmaf(p0, wc[0], dw_b[c]);
        float a1 = p1 * wc[1];
        float a2 = p2 * wc[2];
        a0 = fmaf(p3, wc[3], a0);
        a1 = fmaf(p4, wc[4], a1);
        a2 = fmaf(p5, wc[5], a2);
        a0 = fmaf(p6, wc[6], a0);
        a1 = fmaf(p7, wc[7], a1);
        a2 = fmaf(p8, wc[8], a2);
        const float hc = a0 + a1 + a2;   // depthwise conv output, channel c
        #pragma unroll
        for (int o = 0; o < 48; ++o)
            t[o] = fmaf(hc, pw1_w[o * Cc + c], t[o]);   // wave-uniform weight -> scalar load
    }

    // pw2 (48 -> 9) with fused LeakyReLU(0.2)
    float kw[9];
    #pragma unroll
    for (int k = 0; k < 9; ++k) kw[k] = pw2_b[k];
    #pragma unroll
    for (int o = 0; o < 48; ++o) {
        const float v = t[o];
        const float a = (v >= 0.f) ? v : 0.2f * v;
        #pragma unroll
        for (int k = 0; k < 9; ++k)
            kw[k] = fmaf(a, pw2_w[k * 48 + o], kw[k]);
    }

    // softmax over the 9 kernel weights
    float m = kw[0];
    #pragma unroll
    for (int k = 1; k < 9; ++k) m = fmaxf(m, kw[k]);
    float s = 0.f;
    #pragma unroll
    for (int k = 0; k < 9; ++k) { kw[k] = __expf(kw[k] - m); s += kw[k]; }
    const float inv = 1.f / s;
    #pragma unroll
    for (int k = 0; k < 9; ++k) kw[k] *= inv;

    // smoothing: apply predicted 3x3 kernel to every channel's patch
    float* __restrict__ ob = out + (size_t)b * Cc * HWsz + (size_t)(y0 + sy) * Ww + (x0 + sx);
    for (int c = 0; c < Cc; ++c) {
        const float* lp = lx + c * LPLANE + pbase;
        float a0 = lp[0] * kw[0];
        float a1 = lp[1] * kw[1];
        float a2 = lp[2] * kw[2];
        a0 = fmaf(lp[LROW],     kw[3], a0);
        a1 = fmaf(lp[LROW+1],   kw[4], a1);
        a2 = fmaf(lp[LROW+2],   kw[5], a2);
        a0 = fmaf(lp[2*LROW],   kw[6], a0);
        a1 = fmaf(lp[2*LROW+1], kw[7], a1);
        a2 = fmaf(lp[2*LROW+2], kw[8], a2);
        ob[c * HWsz] = a0 + a1 + a2;
    }
}

extern "C" void kernel_launch(void* const* d_in, const int* in_sizes, int n_in,
                              void* d_out, int out_size, void* d_ws, size_t ws_size,
                              hipStream_t stream)
{
    const float* x     = (const float*)d_in[0];
    const float* dw_w  = (const float*)d_in[1];
    const float* dw_b  = (const float*)d_in[2];
    const float* pw1_w = (const float*)d_in[3];
    const float* pw1_b = (const float*)d_in[4];
    const float* pw2_w = (const float*)d_in[5];
    const float* pw2_b = (const float*)d_in[6];
    float* outp = (float*)d_out;

    const int B = in_sizes[0] / (Cc * HWsz);   // 8
    dim3 grid(Ww / TW, Hh / TH, B);
    alpf_fused<<<grid, 128, 0, stream>>>(x, dw_w, dw_b, pw1_w, pw1_b, pw2_w, pw2_b, outp);
}